// Round 1
// baseline (16646.213 us; speedup 1.0000x reference)
//
#include <hip/hip_runtime.h>
#include <hip/hip_bf16.h>
#include <stdint.h>

// ---------------- problem constants ----------------
// B=64, T=512, D=128, H=512, C=256
#define NWG 128
#define NPHASE 1027
#define SMEM_BYTES (136*1024)

using short8 = __attribute__((ext_vector_type(8))) short;
using f32x4  = __attribute__((ext_vector_type(4))) float;

// ---------------- workspace layout (bytes) ----------------
#define SXY  (64*512*128*2)          // 8,388,608 bf16 x or y
#define OXBF 0
#define OYBF (OXBF + SXY)
#define S0B  (2048*640*2)            // cell0 weight blob (2.6MB)
#define S1B  (2048*1024*2)           // cell1 weight blob (4.2MB)
#define OWE0 (OYBF + SXY)
#define OWD0 (OWE0 + S0B)
#define OWE1 (OWD0 + S0B)
#define OWD1 (OWE1 + S1B)
#define OWC1 (OWD1 + S1B)            // clf W1 blob 262144
#define OWC2 (OWC1 + 262144)         // clf W2 blob 65536
#define OH0  (OWC2 + 65536)          // h0 pub [2][64][512] bf16 = 131072
#define OH1  (OH0 + 131072)
#define OHID (OH1 + 131072)          // hid pub [2][64][256] bf16 = 65536
#define OBAR (OHID + 65536)          // barrier words (256 B)
#define WS_NEEDED (OBAR + 256)

// ---------------- helpers ----------------
static __device__ __forceinline__ unsigned short f2bf(float f){
  union { float f; unsigned u; } v; v.f = f;
  unsigned r = v.u + 0x7FFFu + ((v.u >> 16) & 1u);
  return (unsigned short)(r >> 16);
}
static __device__ __forceinline__ float sigm(float x){ return 1.f/(1.f+__expf(-x)); }
static __device__ __forceinline__ float tanh_(float x){ return 1.f - 2.f/(__expf(2.f*x)+1.f); }

// ---------------- prep kernels ----------------
__global__ void k_init(float* __restrict__ out, uint8_t* __restrict__ ws){
  int i = blockIdx.x*blockDim.x + threadIdx.x;
  int ns = gridDim.x*blockDim.x;
  uint32_t* z = (uint32_t*)(ws + OH0);
  const int n32 = (131072*2 + 65536 + 256)/4;   // h0,h1,hid pubs + barrier
  for (int k=i; k<n32; k+=ns) z[k] = 0u;
  for (int k=i; k<64*128; k+=ns) out[(size_t)(k>>7)*(512*128) + (k&127)] = 0.f;
}

__global__ void k_cvt(const float* __restrict__ x, const float* __restrict__ y,
                      uint8_t* __restrict__ ws){
  unsigned short* xb = (unsigned short*)(ws + OXBF);
  unsigned short* yb = (unsigned short*)(ws + OYBF);
  const int n = 64*512*128;
  int i = blockIdx.x*blockDim.x + threadIdx.x, ns = gridDim.x*blockDim.x;
  for (int k=i; k<n; k+=ns){ xb[k] = f2bf(x[k]); yb[k] = f2bf(y[k]); }
}

// gate-cell weight swizzle into fragment order:
// frag idx = ((((ub*4 + w)*NKK + kk)*4 + g)*64 + lane), 8 bf16 each
// k = w*KC + kk*32 + (lane>>4)*8 + j ; col unit u = ub*16 + (lane&15); row = g*512+u
__global__ void k_swzgate(const float* __restrict__ Wih, const float* __restrict__ Whh,
                          uint8_t* __restrict__ ws, size_t dstOff, int Kin, int KC, int NKK){
  unsigned short* dst = (unsigned short*)(ws + dstOff);
  const int total = 2048 * (KC*4);
  int i = blockIdx.x*blockDim.x + threadIdx.x, ns = gridDim.x*blockDim.x;
  for (int idx=i; idx<total; idx+=ns){
    int j = idx & 7;
    int lane = (idx >> 3) & 63;
    int t = idx >> 9;
    int g = t & 3; t >>= 2;
    int kk = t % NKK; t /= NKK;
    int w = t & 3; int ub = t >> 2;
    int k = w*KC + kk*32 + ((lane>>4)<<3) + j;
    int u = ub*16 + (lane&15);
    int row = g*512 + u;
    float v = (k < Kin) ? Wih[(size_t)row*Kin + k] : Whh[(size_t)row*512 + (k-Kin)];
    dst[idx] = f2bf(v);
  }
}

// clf weight swizzle: frag idx = (((wg*4 + w)*NKK + kk)*64 + lane)
__global__ void k_swzclf(const float* __restrict__ W, uint8_t* __restrict__ ws,
                         size_t dstOff, int nwgs, int Kw, int Ktot){
  unsigned short* dst = (unsigned short*)(ws + dstOff);
  const int NKK = Kw/32;
  const int total = nwgs*4*NKK*64*8;
  int i = blockIdx.x*blockDim.x + threadIdx.x, ns = gridDim.x*blockDim.x;
  for (int idx=i; idx<total; idx+=ns){
    int j = idx & 7;
    int lane = (idx >> 3) & 63;
    int t = idx >> 9;
    int kk = t % NKK; t /= NKK;
    int w = t & 3; int wg = t >> 2;
    int k = w*Kw + kk*32 + ((lane>>4)<<3) + j;
    int col = wg*16 + (lane&15);
    dst[idx] = f2bf(W[(size_t)col*Ktot + k]);
  }
}

// ---------------- persistent kernel ----------------
__launch_bounds__(256, 1)
__global__ void k_seq(uint8_t* __restrict__ ws,
                      const float* __restrict__ eb0, const float* __restrict__ eb1,
                      const float* __restrict__ db0, const float* __restrict__ db1,
                      const float* __restrict__ cb1, const float* __restrict__ cb2,
                      float* __restrict__ out){
  __shared__ uint8_t smem[SMEM_BYTES];
  const int wg = blockIdx.x, tid = threadIdx.x;
  const int w = tid>>6, l = tid&63, lr = l&15, lg = l>>4;
  const bool isC0 = wg < 64;
  const int cwg = isC0 ? wg : wg-64;
  const int bt = cwg>>5, ub = cwg&31;
  const int NKK = isC0 ? 5 : 8;
  const size_t bsz = (size_t)4*NKK*4*64*16;   // 80KB (cell0) / 128KB (cell1)

  const unsigned short* xb = (const unsigned short*)(ws+OXBF);
  const unsigned short* yb = (const unsigned short*)(ws+OYBF);
  unsigned short* h0p = (unsigned short*)(ws+OH0);
  unsigned short* h1p = (unsigned short*)(ws+OH1);
  unsigned short* hpb = (unsigned short*)(ws+OHID);
  unsigned* bcnt = (unsigned*)(ws+OBAR);
  unsigned* brel = (unsigned*)(ws+OBAR+64);

  short8* BL   = (short8*)smem;
  float*  PART = (float*)(smem + bsz);          // [32][4][16] fp32 = 8KB
  short8* HB   = (short8*)(smem + 90112);       // clf weight frags (16KB max)
  float*  HPART= (float*)(smem + 106496);       // [64][16] fp32 = 4KB

  auto loadB = [&](size_t srcOff){
    const uint4* s = (const uint4*)(ws + srcOff);
    uint4* d = (uint4*)smem;
    const int n = (int)(bsz/16);
    for (int i=tid; i<n; i+=256) d[i] = s[i];
  };

  loadB((isC0?(size_t)OWE0:(size_t)OWE1) + (size_t)ub*bsz);
  if (isC0 && wg<16){
    const uint4* s = (const uint4*)(ws + OWC1 + (size_t)wg*16384);
    uint4* d = (uint4*)HB;
    for (int i=tid;i<1024;i+=256) d[i]=s[i];
  }
  if (isC0 && wg>=16 && wg<24){
    const uint4* s = (const uint4*)(ws + OWC2 + (size_t)(wg-16)*8192);
    uint4* d = (uint4*)HB;
    for (int i=tid;i<512;i+=256) d[i]=s[i];
  }
  float cA = 0.f, cB = 0.f;   // per-thread c-state (2 slots), owned for whole run
  __syncthreads();

  auto reduce2048 = [&](f32x4 (&acc)[2][4]){
    for (int wv=0; wv<4; ++wv){
      if (w==wv){
        #pragma unroll
        for (int m=0;m<2;++m)
          #pragma unroll
          for (int g=0;g<4;++g)
            #pragma unroll
            for (int r=0;r<4;++r){
              int brow = m*16 + (lg<<2) + r;
              int idx = (brow*4+g)*16 + lr;
              if (wv==0) PART[idx] = acc[m][g][r]; else PART[idx] += acc[m][g][r];
            }
      }
      __syncthreads();
    }
  };

  auto cell0Step = [&](int sG, int t, const unsigned short* xsrc, const float* bias){
    const int parW = sG&1, parR = (sG+1)&1;
    f32x4 acc[2][4];
    #pragma unroll
    for (int m=0;m<2;++m) for (int g=0;g<4;++g) acc[m][g] = (f32x4){0.f,0.f,0.f,0.f};
    for (int kk=0; kk<5; ++kk){
      const int k0 = w*160 + kk*32;
      const int kl = k0 + (lg<<3);
      short8 a[2];
      #pragma unroll
      for (int m=0;m<2;++m){
        const int b = bt*32 + m*16 + lr;
        const unsigned short* ap = (k0 < 128)
          ? xsrc + ((size_t)b*512 + t)*128 + kl
          : h0p + ((size_t)parR*64 + b)*512 + (kl-128);
        a[m] = *(const short8*)ap;
      }
      #pragma unroll
      for (int g=0;g<4;++g){
        short8 bf = BL[((w*5+kk)*4+g)*64 + l];
        acc[0][g] = __builtin_amdgcn_mfma_f32_16x16x32_bf16(a[0], bf, acc[0][g],0,0,0);
        acc[1][g] = __builtin_amdgcn_mfma_f32_16x16x32_bf16(a[1], bf, acc[1][g],0,0,0);
      }
    }
    reduce2048(acc);
    #pragma unroll
    for (int s=0;s<2;++s){
      int sid = tid + s*256;
      int brow = sid>>4, uc = sid&15;
      const float* pp = &PART[brow*64 + uc];
      int ug = ub*16 + uc;
      float gi = pp[0]  + bias[ug];
      float gf = pp[16] + bias[512+ug];
      float gg = pp[32] + bias[1024+ug];
      float go = pp[48] + bias[1536+ug];
      float cprev = s ? cB : cA;
      float c = sigm(gf)*cprev + sigm(gi)*tanh_(gg);
      if (s) cB = c; else cA = c;
      float h = sigm(go)*tanh_(c);
      h0p[((size_t)parW*64 + (bt*32+brow))*512 + ug] = f2bf(h);
    }
  };

  auto cell1Step = [&](int sG, const float* bias){
    const int parW = sG&1, parR = (sG+1)&1;
    f32x4 acc[2][4];
    #pragma unroll
    for (int m=0;m<2;++m) for (int g=0;g<4;++g) acc[m][g] = (f32x4){0.f,0.f,0.f,0.f};
    for (int kk=0; kk<8; ++kk){
      const int k0 = w*256 + kk*32;
      const int kl = k0 + (lg<<3);
      short8 a[2];
      #pragma unroll
      for (int m=0;m<2;++m){
        const int b = bt*32 + m*16 + lr;
        const unsigned short* ap = (k0 < 512)
          ? h0p + ((size_t)parW*64 + b)*512 + kl
          : h1p + ((size_t)parR*64 + b)*512 + (kl-512);
        a[m] = *(const short8*)ap;
      }
      #pragma unroll
      for (int g=0;g<4;++g){
        short8 bf = BL[((w*8+kk)*4+g)*64 + l];
        acc[0][g] = __builtin_amdgcn_mfma_f32_16x16x32_bf16(a[0], bf, acc[0][g],0,0,0);
        acc[1][g] = __builtin_amdgcn_mfma_f32_16x16x32_bf16(a[1], bf, acc[1][g],0,0,0);
      }
    }
    reduce2048(acc);
    #pragma unroll
    for (int s=0;s<2;++s){
      int sid = tid + s*256;
      int brow = sid>>4, uc = sid&15;
      const float* pp = &PART[brow*64 + uc];
      int ug = ub*16 + uc;
      float gi = pp[0]  + bias[ug];
      float gf = pp[16] + bias[512+ug];
      float gg = pp[32] + bias[1024+ug];
      float go = pp[48] + bias[1536+ug];
      float cprev = s ? cB : cA;
      float c = sigm(gf)*cprev + sigm(gi)*tanh_(gg);
      if (s) cB = c; else cA = c;
      float h = sigm(go)*tanh_(c);
      h1p[((size_t)parW*64 + (bt*32+brow))*512 + ug] = f2bf(h);
    }
  };

  auto reduce1024 = [&](f32x4 (&ha)[4]){
    for (int wv=0; wv<4; ++wv){
      if (w==wv){
        #pragma unroll
        for (int m=0;m<4;++m)
          #pragma unroll
          for (int r=0;r<4;++r){
            int idx = (m*16 + (lg<<2) + r)*16 + lr;
            if (wv==0) HPART[idx] = ha[m][r]; else HPART[idx] += ha[m][r];
          }
      }
      __syncthreads();
    }
  };

  auto hidStep = [&](int t2){
    const int par = t2&1;
    f32x4 ha[4];
    #pragma unroll
    for (int m=0;m<4;++m) ha[m] = (f32x4){0.f,0.f,0.f,0.f};
    for (int kk=0; kk<4; ++kk){
      const int kl = w*128 + kk*32 + (lg<<3);
      short8 bf = HB[(w*4+kk)*64 + l];
      #pragma unroll
      for (int m=0;m<4;++m){
        const unsigned short* ap = h1p + ((size_t)par*64 + m*16+lr)*512 + kl;
        short8 a = *(const short8*)ap;
        ha[m] = __builtin_amdgcn_mfma_f32_16x16x32_bf16(a, bf, ha[m],0,0,0);
      }
    }
    reduce1024(ha);
    #pragma unroll
    for (int s=0;s<4;++s){
      int sid = tid + s*256;
      int brow = sid>>4, uc = sid&15;
      float v = HPART[brow*16 + uc];
      int col = wg*16 + uc;
      v += cb1[col]; v = fmaxf(v, 0.f);
      hpb[((size_t)par*64 + brow)*256 + col] = f2bf(v);
    }
  };

  auto logStep = [&](int t3){
    const int par = t3&1;
    f32x4 la[4];
    #pragma unroll
    for (int m=0;m<4;++m) la[m] = (f32x4){0.f,0.f,0.f,0.f};
    for (int kk=0; kk<2; ++kk){
      const int kl = w*64 + kk*32 + (lg<<3);
      short8 bf = HB[(w*2+kk)*64 + l];
      #pragma unroll
      for (int m=0;m<4;++m){
        const unsigned short* ap = hpb + ((size_t)par*64 + m*16+lr)*256 + kl;
        short8 a = *(const short8*)ap;
        la[m] = __builtin_amdgcn_mfma_f32_16x16x32_bf16(a, bf, la[m],0,0,0);
      }
    }
    reduce1024(la);
    #pragma unroll
    for (int s=0;s<4;++s){
      int sid = tid + s*256;
      int brow = sid>>4, uc = sid&15;
      float v = HPART[brow*16 + uc];
      int col = (wg-16)*16 + uc;
      v += cb2[col];
      out[((size_t)brow*512 + (t3+1))*128 + col] = v;
    }
  };

  auto gbar = [&](unsigned ph){
    __syncthreads();
    if (tid==0){
      unsigned old = __hip_atomic_fetch_add(bcnt, 1u, __ATOMIC_ACQ_REL, __HIP_MEMORY_SCOPE_AGENT);
      if (old == (unsigned)(NWG-1)){
        __hip_atomic_store(bcnt, 0u, __ATOMIC_RELAXED, __HIP_MEMORY_SCOPE_AGENT);
        __hip_atomic_store(brel, ph+1u, __ATOMIC_RELEASE, __HIP_MEMORY_SCOPE_AGENT);
      } else {
        while (__hip_atomic_load(brel, __ATOMIC_ACQUIRE, __HIP_MEMORY_SCOPE_AGENT) < ph+1u)
          __builtin_amdgcn_s_sleep(1);
      }
    }
    __syncthreads();
  };

  for (int ph = 0; ph < NPHASE; ++ph){
    if (isC0){
      if (ph < 512)            cell0Step(ph, ph, xb, eb0);
      else if (ph == 512)      loadB((size_t)OWD0 + (size_t)ub*bsz);
      else if (ph < 1024)      cell0Step(ph-1, ph-513, yb, db0);
      if (wg < 16  && ph >= 515 && ph < 1026) hidStep(ph-515);
      if (wg >= 16 && wg < 24 && ph >= 516 && ph < 1027) logStep(ph-516);
    } else {
      if (ph >= 1 && ph < 513)      cell1Step(ph-1, eb1);
      else if (ph == 513)           loadB((size_t)OWD1 + (size_t)ub*bsz);
      else if (ph >= 514 && ph < 1025) cell1Step(ph-2, db1);
    }
    gbar((unsigned)ph);
  }
}

// ---------------- launch ----------------
extern "C" void kernel_launch(void* const* d_in, const int* in_sizes, int n_in,
                              void* d_out, int out_size, void* d_ws, size_t ws_size,
                              hipStream_t stream){
  const float* x   = (const float*)d_in[0];
  const float* y   = (const float*)d_in[1];
  const float* eW0 = (const float*)d_in[2];
  const float* eU0 = (const float*)d_in[3];
  const float* eb0 = (const float*)d_in[4];
  const float* eW1 = (const float*)d_in[5];
  const float* eU1 = (const float*)d_in[6];
  const float* eb1 = (const float*)d_in[7];
  const float* dW0 = (const float*)d_in[8];
  const float* dU0 = (const float*)d_in[9];
  const float* db0 = (const float*)d_in[10];
  const float* dW1 = (const float*)d_in[11];
  const float* dU1 = (const float*)d_in[12];
  const float* db1 = (const float*)d_in[13];
  const float* cW1 = (const float*)d_in[14];
  const float* cb1 = (const float*)d_in[15];
  const float* cW2 = (const float*)d_in[16];
  const float* cb2 = (const float*)d_in[17];
  float* out = (float*)d_out;
  uint8_t* ws = (uint8_t*)d_ws;
  (void)in_sizes; (void)n_in; (void)out_size; (void)ws_size;

  k_init<<<dim3(256), dim3(256), 0, stream>>>(out, ws);
  k_cvt<<<dim3(2048), dim3(256), 0, stream>>>(x, y, ws);
  k_swzgate<<<dim3(1280), dim3(256), 0, stream>>>(eW0, eU0, ws, (size_t)OWE0, 128, 160, 5);
  k_swzgate<<<dim3(1280), dim3(256), 0, stream>>>(dW0, dU0, ws, (size_t)OWD0, 128, 160, 5);
  k_swzgate<<<dim3(2048), dim3(256), 0, stream>>>(eW1, eU1, ws, (size_t)OWE1, 512, 256, 8);
  k_swzgate<<<dim3(2048), dim3(256), 0, stream>>>(dW1, dU1, ws, (size_t)OWD1, 512, 256, 8);
  k_swzclf<<<dim3(256), dim3(256), 0, stream>>>(cW1, ws, (size_t)OWC1, 16, 128, 512);
  k_swzclf<<<dim3(64),  dim3(256), 0, stream>>>(cW2, ws, (size_t)OWC2, 8, 64, 256);
  k_seq<<<dim3(NWG), dim3(256), 0, stream>>>(ws, eb0, eb1, db0, db1, cb1, cb2, out);
}